// Round 5
// baseline (859.811 us; speedup 1.0000x reference)
//
#include <hip/hip_runtime.h>
#include <math.h>

#define NT 17
#define CH 48
#define KCAP 300
#define NITER 30
#define NWAVE 8
// -1/tau * log2(e): sinkhorn runs in base-2 log domain
#define MSCALE2 28.853900817779268f

typedef unsigned long long u64;

// ---- meta layout (ints at ws start, zeroed each launch) ----
// [0..31]   typeCount
// [32..63]  typeOff
// [64..95]  scatterCnt
// [96]      doneFlag
// [98]      NC (number of real chunks)
// [128..127+4*NC] chunkMeta: 4 ints per chunk (type, startSortedRow, nRows, pad)
// [768..784] chunkStart[17] (first chunk id of type)
// [800..816] chunkCnt[17]

__device__ inline u64 packf2(float m, float s) {
  return ((u64)__float_as_uint(s) << 32) | (u64)__float_as_uint(m);
}
__device__ inline float plo(u64 p) { return __uint_as_float((unsigned)p); }
__device__ inline float phi(u64 p) { return __uint_as_float((unsigned)(p >> 32)); }

__device__ inline float selu_f(float x) {
  const float scale = 1.0507009873554804934193349852946f;
  const float alpha = 1.6732632423543772848170429916717f;
  return x > 0.f ? scale * x : scale * alpha * expm1f(x);
}

__global__ void k_hist(const int* __restrict__ jt, int n, int* meta) {
  int i = blockIdx.x * 256 + threadIdx.x;
  if (i < n) atomicAdd(&meta[jt[i]], 1);
  __syncthreads();
  if (threadIdx.x == 0) {
    __threadfence();
    int d = atomicAdd(&meta[96], 1);
    if (d == (int)gridDim.x - 1) {
      int off = 0, nc = 0;
      for (int t = 0; t < NT; t++) {
        int c = __hip_atomic_load(&meta[t], __ATOMIC_RELAXED, __HIP_MEMORY_SCOPE_AGENT);
        meta[32 + t] = off;
        meta[768 + t] = nc;
        int ncs = (c + CH - 1) / CH;
        meta[800 + t] = ncs;
        int pos = off;
        for (int q = 0; q < ncs; q++) {
          int len = c - q * CH; if (len > CH) len = CH;
          meta[128 + 4 * nc + 0] = t;
          meta[128 + 4 * nc + 1] = pos;
          meta[128 + 4 * nc + 2] = len;
          nc++; pos += len;
        }
        off += c;
      }
      meta[98] = nc;
      __threadfence();
    }
  }
}

__global__ void k_scatter(const int* __restrict__ jt, int n, int* meta,
                          int* __restrict__ perm, int* __restrict__ tys) {
  int i = blockIdx.x * 256 + threadIdx.x;
  if (i < n) {
    int t = jt[i];
    int pos = meta[32 + t] + atomicAdd(&meta[64 + t], 1);
    perm[pos] = i;
    tys[pos] = t;
  }
}

// h = selu(emb @ W1 + b1)   (n x D) @ (D x H)
__global__ __launch_bounds__(256) void k_hgemm(const float* __restrict__ A,
    const float* __restrict__ B, const float* __restrict__ bias,
    float* __restrict__ C, int n, int D, int H) {
  __shared__ __align__(16) float As[16][68];
  __shared__ __align__(16) float Bs[16][68];
  int tid = threadIdx.x;
  int i0 = blockIdx.x * 64, j0 = blockIdx.y * 64;
  int tx = tid & 15, ty = tid >> 4;
  int aI = tid & 63, aK = (tid >> 6) << 2;
  int bJ = (tid & 15) << 2, bK = tid >> 4;
  float acc[4][4] = {};
  for (int k0 = 0; k0 < D; k0 += 16) {
    float4 av = *(const float4*)(A + (size_t)(i0 + aI) * D + k0 + aK);
    float4 bv = *(const float4*)(B + (size_t)(k0 + bK) * H + j0 + bJ);
    __syncthreads();
    As[aK + 0][aI] = av.x; As[aK + 1][aI] = av.y; As[aK + 2][aI] = av.z; As[aK + 3][aI] = av.w;
    *(float4*)(&Bs[bK][bJ]) = bv;
    __syncthreads();
#pragma unroll
    for (int kk = 0; kk < 16; kk++) {
      float4 a4 = *(float4*)(&As[kk][ty << 2]);
      float4 b4 = *(float4*)(&Bs[kk][tx << 2]);
      float aa[4] = {a4.x, a4.y, a4.z, a4.w};
      float bb[4] = {b4.x, b4.y, b4.z, b4.w};
#pragma unroll
      for (int p = 0; p < 4; p++)
#pragma unroll
        for (int q = 0; q < 4; q++)
          acc[p][q] = fmaf(aa[p], bb[q], acc[p][q]);
    }
  }
#pragma unroll
  for (int p = 0; p < 4; p++) {
    int i = i0 + (ty << 2) + p;
    float o[4];
#pragma unroll
    for (int q = 0; q < 4; q++) {
      int j = j0 + (tx << 2) + q;
      o[q] = selu_f(acc[p][q] + bias[j]);
    }
    *(float4*)(C + (size_t)i * H + j0 + (tx << 2)) = make_float4(o[0], o[1], o[2], o[3]);
  }
}

// row norms of h (n rows) and prototypes (k rows)
__global__ __launch_bounds__(256) void k_norms(const float* __restrict__ h,
    const float* __restrict__ P, float* __restrict__ hsq, float* __restrict__ psq,
    int n, int H, int k) {
  int wv = threadIdx.x >> 6, lane = threadIdx.x & 63;
  int idx = blockIdx.x * 4 + wv;
  const float* src; float* dst;
  if (idx < n) { src = h + (size_t)idx * H; dst = hsq + idx; }
  else if (idx < n + k) { int j = idx - n; src = P + (size_t)j * H; dst = psq + j; }
  else return;
  float s = 0.f;
  for (int d = lane * 4; d < H; d += 256) {
    float4 v = *(const float4*)(src + d);
    s += v.x * v.x + v.y * v.y + v.z * v.z + v.w * v.w;
  }
#pragma unroll
  for (int o = 32; o; o >>= 1) s += __shfl_xor(s, o);
  if (lane == 0) *dst = s;
}

// Ms[r][j] = -max(0, hsq+psq-2*dot)/tau * log2(e)  (base-2 domain), rows type-sorted
__global__ __launch_bounds__(256) void k_msort(const float* __restrict__ h,
    const float* __restrict__ P, const float* __restrict__ hsq,
    const float* __restrict__ psq, const int* __restrict__ perm,
    float* __restrict__ Ms, int n, int H, int k) {
  __shared__ __align__(16) float As[16][68];
  __shared__ __align__(16) float Bs[16][68];
  __shared__ int gIdx[64];
  int tid = threadIdx.x;
  int i0 = blockIdx.x * 64, j0 = blockIdx.y * 64;
  if (tid < 64) gIdx[tid] = perm[i0 + tid];
  __syncthreads();
  int tx = tid & 15, ty = tid >> 4;
  int aI = tid & 63, aK = (tid >> 6) << 2;
  int gA = gIdx[aI];
  bool bok = (j0 + aI) < k;
  const float* bRow = P + (size_t)(j0 + (bok ? aI : 0)) * H;
  float acc[4][4] = {};
  for (int k0 = 0; k0 < H; k0 += 16) {
    float4 av = *(const float4*)(h + (size_t)gA * H + k0 + aK);
    float4 bv = *(const float4*)(bRow + k0 + aK);
    __syncthreads();
    As[aK + 0][aI] = av.x; As[aK + 1][aI] = av.y; As[aK + 2][aI] = av.z; As[aK + 3][aI] = av.w;
    Bs[aK + 0][aI] = bv.x; Bs[aK + 1][aI] = bv.y; Bs[aK + 2][aI] = bv.z; Bs[aK + 3][aI] = bv.w;
    __syncthreads();
#pragma unroll
    for (int kk = 0; kk < 16; kk++) {
      float4 a4 = *(float4*)(&As[kk][ty << 2]);
      float4 b4 = *(float4*)(&Bs[kk][tx << 2]);
      float aa[4] = {a4.x, a4.y, a4.z, a4.w};
      float bb[4] = {b4.x, b4.y, b4.z, b4.w};
#pragma unroll
      for (int p = 0; p < 4; p++)
#pragma unroll
        for (int q = 0; q < 4; q++)
          acc[p][q] = fmaf(aa[p], bb[q], acc[p][q]);
    }
  }
#pragma unroll
  for (int p = 0; p < 4; p++) {
    int rr = (ty << 2) + p;
    int r = i0 + rr;
    float hq = hsq[gIdx[rr]];
#pragma unroll
    for (int q = 0; q < 4; q++) {
      int j = j0 + (tx << 2) + q;
      if (j < k) {
        float d2 = hq + psq[j] - 2.f * acc[p][q];
        d2 = fmaxf(d2, 0.f);
        Ms[(size_t)r * k + j] = -d2 * MSCALE2;
      }
    }
  }
}

// Persistent Sinkhorn, base-2 log domain, BARRIER-FREE dataflow exchange.
// Each (chunk, iter) partial is published as (data u64, epoch u32): data store,
// s_waitcnt vmcnt(0), epoch store (= m+1, exact-match disambiguates parity reuse).
// Consumers poll only the slots they need. Global coupling (lvl) is polled by
// wave 7 concurrently with the row pass; pl is published early (pre-col-pass).
__global__ __launch_bounds__(512) void k_sink(const float* __restrict__ Ms,
    const int* __restrict__ meta,
    u64* __restrict__ pcD, unsigned* __restrict__ pcE,
    u64* __restrict__ plD, unsigned* __restrict__ plE,
    float* __restrict__ luF, float* __restrict__ VF,
    int k, int NCmax, float l2tm) {
  __shared__ float Mc[KCAP * 49];
  __shared__ float V[KCAP];
  __shared__ float lu[CH];
  __shared__ float rpM[CH];
  __shared__ float rpS[CH];
  __shared__ float lvl_sh;
  int tid = threadIdx.x, lane = tid & 63, wv = tid >> 6;
  int c = blockIdx.x;
  int NC = meta[98];
  if (c >= NC) return;
  int t  = meta[128 + 4 * c + 0];
  int s0 = meta[128 + 4 * c + 1];
  int cR = meta[128 + 4 * c + 2];
  int cS = meta[768 + t];
  int cN = meta[800 + t];

  {
    const float* src = Ms + (size_t)s0 * k;
    for (int r = wv; r < cR; r += NWAVE)
      for (int j = lane; j < k; j += 64)
        Mc[j * 49 + r] = src[(size_t)r * k + j];
  }
  for (int j = tid; j < k; j += 512) V[j] = 0.f;
  if (tid == 0) lvl_sh = 0.f;
  __syncthreads();

  for (int m = 0; m < NITER; m++) {
    int par = m & 1;
    unsigned epoch = (unsigned)(m + 1);
    // ---- phase 1: row partial LSE over columns (waves 0..6) ||
    //               lvl_{m-1} combine from pl (wave 7) ----
    if (wv < 7) {
      for (int r = wv; r < cR; r += 7) {
        float xv[5];
        int cnt = 0;
        for (int j = lane; j < k; j += 64) xv[cnt++] = Mc[j * 49 + r] + V[j];
        float xm = -3.0e38f;
        for (int q = 0; q < cnt; q++) xm = fmaxf(xm, xv[q]);
#pragma unroll
        for (int o = 32; o; o >>= 1) xm = fmaxf(xm, __shfl_xor(xm, o));
        float s = 0.f;
        for (int q = 0; q < cnt; q++) s += exp2f(xv[q] - xm);
#pragma unroll
        for (int o = 32; o; o >>= 1) s += __shfl_xor(s, o);
        if (lane == 0) { rpM[r] = xm; rpS[r] = s; }
      }
    } else if (m > 0) {
      int ppar = (m - 1) & 1;
      unsigned epPrev = (unsigned)m;
      unsigned* pe = plE + (size_t)ppar * NCmax;
      u64* pd = plD + (size_t)ppar * NCmax;
      bool n0 = lane < NC, n1 = lane + 64 < NC, n2 = lane + 128 < NC;
      for (;;) {
        bool ok = true;
        if (n0 && __hip_atomic_load(&pe[lane], __ATOMIC_RELAXED, __HIP_MEMORY_SCOPE_AGENT) != epPrev) ok = false;
        if (n1 && __hip_atomic_load(&pe[lane + 64], __ATOMIC_RELAXED, __HIP_MEMORY_SCOPE_AGENT) != epPrev) ok = false;
        if (n2 && __hip_atomic_load(&pe[lane + 128], __ATOMIC_RELAXED, __HIP_MEMORY_SCOPE_AGENT) != epPrev) ok = false;
        if (__all(ok)) break;
        __builtin_amdgcn_s_sleep(1);
      }
      u64 a0 = n0 ? __hip_atomic_load(&pd[lane], __ATOMIC_RELAXED, __HIP_MEMORY_SCOPE_AGENT) : packf2(-3.0e38f, 0.f);
      u64 a1 = n1 ? __hip_atomic_load(&pd[lane + 64], __ATOMIC_RELAXED, __HIP_MEMORY_SCOPE_AGENT) : packf2(-3.0e38f, 0.f);
      u64 a2 = n2 ? __hip_atomic_load(&pd[lane + 128], __ATOMIC_RELAXED, __HIP_MEMORY_SCOPE_AGENT) : packf2(-3.0e38f, 0.f);
      float mm = fmaxf(fmaxf(plo(a0), plo(a1)), plo(a2));
      float ss = phi(a0) * exp2f(plo(a0) - mm) + phi(a1) * exp2f(plo(a1) - mm) +
                 phi(a2) * exp2f(plo(a2) - mm);
#pragma unroll
      for (int o = 32; o; o >>= 1) {
        float mq = __shfl_xor(mm, o), sq = __shfl_xor(ss, o);
        float nm = fmaxf(mm, mq);
        ss = ss * exp2f(mm - nm) + sq * exp2f(mq - nm);
        mm = nm;
      }
      if (lane == 0) lvl_sh = l2tm - (mm + __log2f(ss));
    }
    __syncthreads();
    // ---- phase 2 (wave 0): merge lvl into lu; publish pl_m EARLY ----
    if (wv == 0) {
      float lvl = lvl_sh;
      float x;
      if (lane < cR) {
        float pm = rpM[lane], ps = rpS[lane];
        float nm = fmaxf(pm, lvl);
        float s = ps * exp2f(pm - nm) + exp2f(lvl - nm);
        x = -(nm + __log2f(s));
        lu[lane] = x;
      } else {
        x = -3.0e38f;
      }
      float mm = x;
#pragma unroll
      for (int o = 32; o; o >>= 1) mm = fmaxf(mm, __shfl_xor(mm, o));
      float e = (lane < cR) ? exp2f(x - mm) : 0.f;
#pragma unroll
      for (int o = 32; o; o >>= 1) e += __shfl_xor(e, o);
      if (lane == 0)
        __hip_atomic_store(&plD[(size_t)par * NCmax + c], packf2(mm, e),
                           __ATOMIC_RELAXED, __HIP_MEMORY_SCOPE_AGENT);
      __builtin_amdgcn_s_waitcnt(0);  // pl data globally visible before epoch
      if (lane == 0)
        __hip_atomic_store(&plE[(size_t)par * NCmax + c], epoch,
                           __ATOMIC_RELAXED, __HIP_MEMORY_SCOPE_AGENT);
    }
    __syncthreads();
    // ---- phase 3: column partials -> publish pc_m ----
    u64* pcDp = pcD + (size_t)par * NCmax * k;
    unsigned* pcEp = pcE + (size_t)par * NCmax * k;
    for (int j = tid; j < k; j += 512) {
      const float* col = &Mc[j * 49];
      float m0 = -3.0e38f, m1 = -3.0e38f, m2 = -3.0e38f, m3 = -3.0e38f;
      int r = 0;
      for (; r + 4 <= cR; r += 4) {
        m0 = fmaxf(m0, col[r + 0] + lu[r + 0]);
        m1 = fmaxf(m1, col[r + 1] + lu[r + 1]);
        m2 = fmaxf(m2, col[r + 2] + lu[r + 2]);
        m3 = fmaxf(m3, col[r + 3] + lu[r + 3]);
      }
      for (; r < cR; r++) m0 = fmaxf(m0, col[r] + lu[r]);
      float mm = fmaxf(fmaxf(m0, m1), fmaxf(m2, m3));
      float sa = 0.f, sb = 0.f, sc = 0.f, sd = 0.f;
      r = 0;
      for (; r + 4 <= cR; r += 4) {
        sa += exp2f(col[r + 0] + lu[r + 0] - mm);
        sb += exp2f(col[r + 1] + lu[r + 1] - mm);
        sc += exp2f(col[r + 2] + lu[r + 2] - mm);
        sd += exp2f(col[r + 3] + lu[r + 3] - mm);
      }
      for (; r < cR; r++) sa += exp2f(col[r] + lu[r] - mm);
      float ss = (sa + sb) + (sc + sd);
      __hip_atomic_store(&pcDp[(size_t)c * k + j], packf2(mm, ss),
                         __ATOMIC_RELAXED, __HIP_MEMORY_SCOPE_AGENT);
    }
    __builtin_amdgcn_s_waitcnt(0);  // pc data globally visible before epochs
    for (int j = tid; j < k; j += 512)
      __hip_atomic_store(&pcEp[(size_t)c * k + j], epoch,
                         __ATOMIC_RELAXED, __HIP_MEMORY_SCOPE_AGENT);
    // ---- phase 4: combine sibling col partials -> V (poll own type only) ----
    for (int j = tid; j < k; j += 512) {
      for (;;) {
        bool ok = true;
#pragma unroll
        for (int q = 0; q < 12; q++)
          if (q < cN &&
              __hip_atomic_load(&pcEp[(size_t)(cS + q) * k + j],
                                __ATOMIC_RELAXED, __HIP_MEMORY_SCOPE_AGENT) != epoch)
            ok = false;
        if (ok) break;
        __builtin_amdgcn_s_sleep(1);
      }
      u64 pk[12];
#pragma unroll
      for (int q = 0; q < 12; q++)
        pk[q] = (q < cN)
            ? __hip_atomic_load(&pcDp[(size_t)(cS + q) * k + j],
                                __ATOMIC_RELAXED, __HIP_MEMORY_SCOPE_AGENT)
            : packf2(-3.0e38f, 0.f);
      float mm = -3.0e38f;
#pragma unroll
      for (int q = 0; q < 12; q++) mm = fmaxf(mm, plo(pk[q]));
      float ss = 0.f;
#pragma unroll
      for (int q = 0; q < 12; q++) ss += phi(pk[q]) * exp2f(plo(pk[q]) - mm);
      V[j] = -(mm + __log2f(ss));
    }
    __syncthreads();
  }
  for (int r = tid; r < cR; r += 512) luF[s0 + r] = lu[r];
  if (c == cS)
    for (int j = tid; j < k; j += 512) VF[(size_t)t * k + j] = V[j];
}

// epilogue (base-2): logits = log(exp2(M+lu+V)+1e-8); T row scatter into j*17+t
__global__ __launch_bounds__(256) void k_epi(const float* __restrict__ Ms,
    const float* __restrict__ luF, const float* __restrict__ VF,
    const int* __restrict__ perm, const int* __restrict__ tys,
    float* __restrict__ out, int n, int k) {
  __shared__ float vals[KCAP];
  int r = blockIdx.x;
  int i = perm[r], t = tys[r];
  float lu = luF[r];
  const float* Mrow = Ms + (size_t)r * k;
  const float* Vrow = VF + (size_t)t * k;
  for (int j = threadIdx.x; j < k; j += 256) vals[j] = exp2f(Mrow[j] + lu + Vrow[j]);
  __syncthreads();
  float* lg = out + (size_t)i * k;
  for (int j = threadIdx.x; j < k; j += 256) lg[j] = logf(vals[j] + 1e-8f);
  int ns = k * NT;
  float* Trow = out + (size_t)n * k + (size_t)i * ns;
  if ((ns & 3) == 0 && (((size_t)n * k) & 3) == 0) {
    int n4 = ns >> 2;
    for (int g4 = threadIdx.x; g4 < n4; g4 += 256) {
      int o0 = g4 << 2;
      float v[4] = {0.f, 0.f, 0.f, 0.f};
#pragma unroll
      for (int s = 0; s < 4; s++) {
        int o = o0 + s;
        int j = o / NT;
        int tt = o - j * NT;
        if (tt == t) v[s] = vals[j];
      }
      *(float4*)(Trow + o0) = make_float4(v[0], v[1], v[2], v[3]);
    }
  } else {
    for (int o = threadIdx.x; o < ns; o += 256) {
      int j = o / NT;
      int tt = o - j * NT;
      Trow[o] = (tt == t) ? vals[j] : 0.f;
    }
  }
}

extern "C" void kernel_launch(void* const* d_in, const int* in_sizes, int n_in,
                              void* d_out, int out_size, void* d_ws, size_t ws_size,
                              hipStream_t stream) {
  const float* emb = (const float*)d_in[0];
  const float* W1  = (const float*)d_in[1];
  const float* b1  = (const float*)d_in[2];
  const float* P   = (const float*)d_in[3];
  const int*   jt  = (const int*)d_in[4];
  (void)n_in; (void)ws_size;

  const int n = in_sizes[4];
  const int H = in_sizes[2];
  const int D = in_sizes[1] / H;
  const int k = out_size / (n * (NT + 1));
  const int nslots = k * NT;
  const float tm_last = (float)((n - nslots) > 1 ? (n - nslots) : 1);
  const float l2tm = log2f(tm_last);
  const int NCmax = NT + (n + CH - 1) / CH;

  char* w = (char*)d_ws;
  size_t off = 0;
  auto take = [&](size_t bytes) -> char* {
    char* p = w + off;
    off = (off + bytes + 255) & ~(size_t)255;
    return p;
  };
  int*      meta = (int*)take(4096);
  int*      perm = (int*)take((size_t)n * 4);
  int*      tys  = (int*)take((size_t)n * 4);
  float*    h    = (float*)take((size_t)n * H * 4);
  float*    hsq  = (float*)take((size_t)n * 4);
  float*    psq  = (float*)take((size_t)k * 4);
  float*    Ms   = (float*)take((size_t)n * k * 4);
  u64*      pcD  = (u64*)take((size_t)2 * NCmax * k * 8);
  unsigned* pcE  = (unsigned*)take((size_t)2 * NCmax * k * 4);
  u64*      plD  = (u64*)take((size_t)2 * NCmax * 8);
  unsigned* plE  = (unsigned*)take((size_t)2 * NCmax * 4);
  float*    luF  = (float*)take((size_t)n * 4);
  float*    VF   = (float*)take((size_t)NT * k * 4);

  (void)hipMemsetAsync(meta, 0, 4096, stream);
  // epoch arrays: any prior content (0xAA poison or stale epochs from the same
  // layout) never equals a fresh m+1 exact-match in this launch's sequence
  // only if cleared; clear to 0 to be unconditionally safe.
  (void)hipMemsetAsync(pcE, 0, (size_t)2 * NCmax * k * 4, stream);
  (void)hipMemsetAsync(plE, 0, (size_t)2 * NCmax * 4, stream);
  k_hist<<<(n + 255) / 256, 256, 0, stream>>>(jt, n, meta);
  k_scatter<<<(n + 255) / 256, 256, 0, stream>>>(jt, n, meta, perm, tys);
  k_hgemm<<<dim3(n / 64, H / 64), dim3(256), 0, stream>>>(emb, W1, b1, h, n, D, H);
  k_norms<<<(n + k + 3) / 4, 256, 0, stream>>>(h, P, hsq, psq, n, H, k);
  k_msort<<<dim3(n / 64, (k + 63) / 64), dim3(256), 0, stream>>>(h, P, hsq, psq, perm, Ms, n, H, k);
  k_sink<<<NCmax, 512, 0, stream>>>(Ms, meta, pcD, pcE, plD, plE, luF, VF, k, NCmax, l2tm);
  k_epi<<<n, 256, 0, stream>>>(Ms, luF, VF, perm, tys, (float*)d_out, n, k);
}

// Round 6
// 739.136 us; speedup vs baseline: 1.1633x; 1.1633x over previous
//
#include <hip/hip_runtime.h>
#include <math.h>

#define NT 17
#define CH 48
#define KCAP 300
#define NITER 30
#define NWAVE 8
// -1/tau * log2(e): sinkhorn runs in base-2 log domain
#define MSCALE2 28.853900817779268f

typedef unsigned long long u64;

#define EX2(x) __builtin_amdgcn_exp2f(x)
#define LG2(x) __builtin_amdgcn_logf(x)

// ---- meta layout (ints at ws start, zeroed each launch) ----
// [0..31]   typeCount
// [32..63]  typeOff
// [64..95]  scatterCnt
// [96]      doneFlag
// [98]      NC (number of real chunks)
// [128..127+4*NC] chunkMeta: 4 ints per chunk (type, startSortedRow, nRows, pad)
// [768..784] chunkStart[17] (first chunk id of type)
// [800..816] chunkCnt[17]

__device__ inline u64 packf2(float m, float s) {
  return ((u64)__float_as_uint(s) << 32) | (u64)__float_as_uint(m);
}
__device__ inline float plo(u64 p) { return __uint_as_float((unsigned)p); }
__device__ inline float phi(u64 p) { return __uint_as_float((unsigned)(p >> 32)); }

__device__ inline float selu_f(float x) {
  const float scale = 1.0507009873554804934193349852946f;
  const float alpha = 1.6732632423543772848170429916717f;
  return x > 0.f ? scale * x : scale * alpha * (EX2(x * 1.4426950408889634f) - 1.f);
}

__global__ void k_hist(const int* __restrict__ jt, int n, int* meta) {
  int i = blockIdx.x * 256 + threadIdx.x;
  if (i < n) atomicAdd(&meta[jt[i]], 1);
  __syncthreads();
  if (threadIdx.x == 0) {
    __threadfence();
    int d = atomicAdd(&meta[96], 1);
    if (d == (int)gridDim.x - 1) {
      int off = 0, nc = 0;
      for (int t = 0; t < NT; t++) {
        int c = __hip_atomic_load(&meta[t], __ATOMIC_RELAXED, __HIP_MEMORY_SCOPE_AGENT);
        meta[32 + t] = off;
        meta[768 + t] = nc;
        int ncs = (c + CH - 1) / CH;
        meta[800 + t] = ncs;
        int pos = off;
        for (int q = 0; q < ncs; q++) {
          int len = c - q * CH; if (len > CH) len = CH;
          meta[128 + 4 * nc + 0] = t;
          meta[128 + 4 * nc + 1] = pos;
          meta[128 + 4 * nc + 2] = len;
          nc++; pos += len;
        }
        off += c;
      }
      meta[98] = nc;
      __threadfence();
    }
  }
}

__global__ void k_scatter(const int* __restrict__ jt, int n, int* meta,
                          int* __restrict__ perm, int* __restrict__ tys) {
  int i = blockIdx.x * 256 + threadIdx.x;
  if (i < n) {
    int t = jt[i];
    int pos = meta[32 + t] + atomicAdd(&meta[64 + t], 1);
    perm[pos] = i;
    tys[pos] = t;
  }
}

// h = selu(emb @ W1 + b1)   (n x D) @ (D x H)
__global__ __launch_bounds__(256) void k_hgemm(const float* __restrict__ A,
    const float* __restrict__ B, const float* __restrict__ bias,
    float* __restrict__ C, int n, int D, int H) {
  __shared__ __align__(16) float As[16][68];
  __shared__ __align__(16) float Bs[16][68];
  int tid = threadIdx.x;
  int i0 = blockIdx.x * 64, j0 = blockIdx.y * 64;
  int tx = tid & 15, ty = tid >> 4;
  int aI = tid & 63, aK = (tid >> 6) << 2;
  int bJ = (tid & 15) << 2, bK = tid >> 4;
  float acc[4][4] = {};
  for (int k0 = 0; k0 < D; k0 += 16) {
    float4 av = *(const float4*)(A + (size_t)(i0 + aI) * D + k0 + aK);
    float4 bv = *(const float4*)(B + (size_t)(k0 + bK) * H + j0 + bJ);
    __syncthreads();
    As[aK + 0][aI] = av.x; As[aK + 1][aI] = av.y; As[aK + 2][aI] = av.z; As[aK + 3][aI] = av.w;
    *(float4*)(&Bs[bK][bJ]) = bv;
    __syncthreads();
#pragma unroll
    for (int kk = 0; kk < 16; kk++) {
      float4 a4 = *(float4*)(&As[kk][ty << 2]);
      float4 b4 = *(float4*)(&Bs[kk][tx << 2]);
      float aa[4] = {a4.x, a4.y, a4.z, a4.w};
      float bb[4] = {b4.x, b4.y, b4.z, b4.w};
#pragma unroll
      for (int p = 0; p < 4; p++)
#pragma unroll
        for (int q = 0; q < 4; q++)
          acc[p][q] = fmaf(aa[p], bb[q], acc[p][q]);
    }
  }
#pragma unroll
  for (int p = 0; p < 4; p++) {
    int i = i0 + (ty << 2) + p;
    float o[4];
#pragma unroll
    for (int q = 0; q < 4; q++) {
      int j = j0 + (tx << 2) + q;
      o[q] = selu_f(acc[p][q] + bias[j]);
    }
    *(float4*)(C + (size_t)i * H + j0 + (tx << 2)) = make_float4(o[0], o[1], o[2], o[3]);
  }
}

// row norms of h (n rows) and prototypes (k rows)
__global__ __launch_bounds__(256) void k_norms(const float* __restrict__ h,
    const float* __restrict__ P, float* __restrict__ hsq, float* __restrict__ psq,
    int n, int H, int k) {
  int wv = threadIdx.x >> 6, lane = threadIdx.x & 63;
  int idx = blockIdx.x * 4 + wv;
  const float* src; float* dst;
  if (idx < n) { src = h + (size_t)idx * H; dst = hsq + idx; }
  else if (idx < n + k) { int j = idx - n; src = P + (size_t)j * H; dst = psq + j; }
  else return;
  float s = 0.f;
  for (int d = lane * 4; d < H; d += 256) {
    float4 v = *(const float4*)(src + d);
    s += v.x * v.x + v.y * v.y + v.z * v.z + v.w * v.w;
  }
#pragma unroll
  for (int o = 32; o; o >>= 1) s += __shfl_xor(s, o);
  if (lane == 0) *dst = s;
}

// Ms[r][j] = -max(0, hsq+psq-2*dot)/tau * log2(e)  (base-2 domain), rows type-sorted
__global__ __launch_bounds__(256) void k_msort(const float* __restrict__ h,
    const float* __restrict__ P, const float* __restrict__ hsq,
    const float* __restrict__ psq, const int* __restrict__ perm,
    float* __restrict__ Ms, int n, int H, int k) {
  __shared__ __align__(16) float As[16][68];
  __shared__ __align__(16) float Bs[16][68];
  __shared__ int gIdx[64];
  int tid = threadIdx.x;
  int i0 = blockIdx.x * 64, j0 = blockIdx.y * 64;
  if (tid < 64) gIdx[tid] = perm[i0 + tid];
  __syncthreads();
  int tx = tid & 15, ty = tid >> 4;
  int aI = tid & 63, aK = (tid >> 6) << 2;
  int gA = gIdx[aI];
  bool bok = (j0 + aI) < k;
  const float* bRow = P + (size_t)(j0 + (bok ? aI : 0)) * H;
  float acc[4][4] = {};
  for (int k0 = 0; k0 < H; k0 += 16) {
    float4 av = *(const float4*)(h + (size_t)gA * H + k0 + aK);
    float4 bv = *(const float4*)(bRow + k0 + aK);
    __syncthreads();
    As[aK + 0][aI] = av.x; As[aK + 1][aI] = av.y; As[aK + 2][aI] = av.z; As[aK + 3][aI] = av.w;
    Bs[aK + 0][aI] = bv.x; Bs[aK + 1][aI] = bv.y; Bs[aK + 2][aI] = bv.z; Bs[aK + 3][aI] = bv.w;
    __syncthreads();
#pragma unroll
    for (int kk = 0; kk < 16; kk++) {
      float4 a4 = *(float4*)(&As[kk][ty << 2]);
      float4 b4 = *(float4*)(&Bs[kk][tx << 2]);
      float aa[4] = {a4.x, a4.y, a4.z, a4.w};
      float bb[4] = {b4.x, b4.y, b4.z, b4.w};
#pragma unroll
      for (int p = 0; p < 4; p++)
#pragma unroll
        for (int q = 0; q < 4; q++)
          acc[p][q] = fmaf(aa[p], bb[q], acc[p][q]);
    }
  }
#pragma unroll
  for (int p = 0; p < 4; p++) {
    int rr = (ty << 2) + p;
    int r = i0 + rr;
    float hq = hsq[gIdx[rr]];
#pragma unroll
    for (int q = 0; q < 4; q++) {
      int j = j0 + (tx << 2) + q;
      if (j < k) {
        float d2 = hq + psq[j] - 2.f * acc[p][q];
        d2 = fmaxf(d2, 0.f);
        Ms[(size_t)r * k + j] = -d2 * MSCALE2;
      }
    }
  }
}

// Persistent Sinkhorn, base-2 log domain. Decentralized per-type dataflow:
// chunk-level epoch words on padded cache lines (<=9 pollers per line);
// global lvl coupling via type-leader hierarchy (pl -> tpl -> lvl), polled by
// wave 7 concurrently with the row pass (off critical path).
__global__ __launch_bounds__(512) void k_sink(const float* __restrict__ Ms,
    const int* __restrict__ meta,
    u64* __restrict__ pcD, unsigned* __restrict__ pcE,
    u64* __restrict__ plD, unsigned* __restrict__ plE,
    u64* __restrict__ tplD, unsigned* __restrict__ tplE,
    float* __restrict__ luF, float* __restrict__ VF,
    int k, int NCmax, float l2tm) {
  __shared__ float Mc[KCAP * 49];
  __shared__ float V[KCAP];
  __shared__ float lu[CH];
  __shared__ float rpM[CH];
  __shared__ float rpS[CH];
  __shared__ float lvl_sh;
  int tid = threadIdx.x, lane = tid & 63, wv = tid >> 6;
  int c = blockIdx.x;
  int NC = meta[98];
  if (c >= NC) return;
  int t  = meta[128 + 4 * c + 0];
  int s0 = meta[128 + 4 * c + 1];
  int cR = meta[128 + 4 * c + 2];
  int cS = meta[768 + t];
  int cN = meta[800 + t];
  bool leader = (c == cS);
  // wave-7 helper: per-lane type mask for tpl poll
  int laneTypeCnt = (lane < NT) ? meta[800 + lane] : 0;

  {
    const float* src = Ms + (size_t)s0 * k;
    for (int r = wv; r < cR; r += NWAVE)
      for (int j = lane; j < k; j += 64)
        Mc[j * 49 + r] = src[(size_t)r * k + j];
  }
  for (int j = tid; j < k; j += 512) V[j] = 0.f;
  if (tid == 0) lvl_sh = 0.f;
  __syncthreads();

  for (int m = 0; m < NITER; m++) {
    int par = m & 1;
    unsigned epoch = (unsigned)(m + 1);
    // ---- P1: row partial LSE over columns (waves 0..6) ||
    //          lvl_{m-1} from tpl (wave 7) ----
    if (wv < 7) {
      for (int r = wv; r < cR; r += 7) {
        float xv[5];
        int cnt = 0;
        for (int j = lane; j < k; j += 64) xv[cnt++] = Mc[j * 49 + r] + V[j];
        float xm = -3.0e38f;
        for (int q = 0; q < cnt; q++) xm = fmaxf(xm, xv[q]);
#pragma unroll
        for (int o = 32; o; o >>= 1) xm = fmaxf(xm, __shfl_xor(xm, o));
        float s = 0.f;
        for (int q = 0; q < cnt; q++) s += EX2(xv[q] - xm);
#pragma unroll
        for (int o = 32; o; o >>= 1) s += __shfl_xor(s, o);
        if (lane == 0) { rpM[r] = xm; rpS[r] = s; }
      }
    } else if (m > 0) {
      int ppar = (m - 1) & 1;
      unsigned epPrev = (unsigned)m;
      bool need = (lane < NT) && (laneTypeCnt > 0);
      unsigned* te = tplE + (size_t)ppar * NT * 16;
      for (;;) {
        bool ok = !need ||
            (__hip_atomic_load(&te[lane * 16], __ATOMIC_RELAXED, __HIP_MEMORY_SCOPE_AGENT) == epPrev);
        if (__all(ok)) break;
        __builtin_amdgcn_s_sleep(2);
      }
      u64 a = need
          ? __hip_atomic_load(&tplD[((size_t)ppar * NT + lane) * 8],
                              __ATOMIC_RELAXED, __HIP_MEMORY_SCOPE_AGENT)
          : packf2(-3.0e38f, 0.f);
      float mm = plo(a), ss = phi(a);
#pragma unroll
      for (int o = 32; o; o >>= 1) {
        float mq = __shfl_xor(mm, o), sq = __shfl_xor(ss, o);
        float nm = fmaxf(mm, mq);
        ss = ss * EX2(mm - nm) + sq * EX2(mq - nm);
        mm = nm;
      }
      if (lane == 0) lvl_sh = l2tm - (mm + LG2(ss));
    }
    __syncthreads();
    // ---- P2 (wave 0): merge lvl into lu; publish pl (data, drain, epoch) ----
    if (wv == 0) {
      float lvl = lvl_sh;
      float x;
      if (lane < cR) {
        float pm = rpM[lane], ps = rpS[lane];
        float nm = fmaxf(pm, lvl);
        float s = ps * EX2(pm - nm) + EX2(lvl - nm);
        x = -(nm + LG2(s));
        lu[lane] = x;
      } else {
        x = -3.0e38f;
      }
      float mm = x;
#pragma unroll
      for (int o = 32; o; o >>= 1) mm = fmaxf(mm, __shfl_xor(mm, o));
      float e = (lane < cR) ? EX2(x - mm) : 0.f;
#pragma unroll
      for (int o = 32; o; o >>= 1) e += __shfl_xor(e, o);
      if (lane == 0)
        __hip_atomic_store(&plD[((size_t)par * NCmax + c) * 8], packf2(mm, e),
                           __ATOMIC_RELAXED, __HIP_MEMORY_SCOPE_AGENT);
      __builtin_amdgcn_s_waitcnt(0);
      if (lane == 0)
        __hip_atomic_store(&plE[((size_t)par * NCmax + c) * 16], epoch,
                           __ATOMIC_RELAXED, __HIP_MEMORY_SCOPE_AGENT);
    }
    __syncthreads();
    // ---- P3: column partials (threads j<k) || leader wave 7: pl -> tpl ----
    u64* pcDp = pcD + (size_t)par * NCmax * k;
    for (int j = tid; j < k; j += 512) {
      const float* col = &Mc[j * 49];
      float m0 = -3.0e38f, m1 = -3.0e38f, m2 = -3.0e38f, m3 = -3.0e38f;
      int r = 0;
      for (; r + 4 <= cR; r += 4) {
        m0 = fmaxf(m0, col[r + 0] + lu[r + 0]);
        m1 = fmaxf(m1, col[r + 1] + lu[r + 1]);
        m2 = fmaxf(m2, col[r + 2] + lu[r + 2]);
        m3 = fmaxf(m3, col[r + 3] + lu[r + 3]);
      }
      for (; r < cR; r++) m0 = fmaxf(m0, col[r] + lu[r]);
      float mm = fmaxf(fmaxf(m0, m1), fmaxf(m2, m3));
      float sa = 0.f, sb = 0.f, sc = 0.f, sd = 0.f;
      r = 0;
      for (; r + 4 <= cR; r += 4) {
        sa += EX2(col[r + 0] + lu[r + 0] - mm);
        sb += EX2(col[r + 1] + lu[r + 1] - mm);
        sc += EX2(col[r + 2] + lu[r + 2] - mm);
        sd += EX2(col[r + 3] + lu[r + 3] - mm);
      }
      for (; r < cR; r++) sa += EX2(col[r] + lu[r] - mm);
      float ss = (sa + sb) + (sc + sd);
      __hip_atomic_store(&pcDp[(size_t)c * k + j], packf2(mm, ss),
                         __ATOMIC_RELAXED, __HIP_MEMORY_SCOPE_AGENT);
    }
    if (leader && wv == 7) {
      // combine own type's pl partials -> tpl (lanes 0..cN-1)
      bool need = lane < cN;
      unsigned* pe = plE + (size_t)par * NCmax * 16;
      for (;;) {
        bool ok = !need ||
            (__hip_atomic_load(&pe[(cS + lane) * 16], __ATOMIC_RELAXED, __HIP_MEMORY_SCOPE_AGENT) == epoch);
        if (__all(ok)) break;
        __builtin_amdgcn_s_sleep(1);
      }
      u64 a = need
          ? __hip_atomic_load(&plD[((size_t)par * NCmax + cS + lane) * 8],
                              __ATOMIC_RELAXED, __HIP_MEMORY_SCOPE_AGENT)
          : packf2(-3.0e38f, 0.f);
      float mm = plo(a), ss = phi(a);
#pragma unroll
      for (int o = 32; o; o >>= 1) {
        float mq = __shfl_xor(mm, o), sq = __shfl_xor(ss, o);
        float nm = fmaxf(mm, mq);
        ss = ss * EX2(mm - nm) + sq * EX2(mq - nm);
        mm = nm;
      }
      if (lane == 0)
        __hip_atomic_store(&tplD[((size_t)par * NT + t) * 8], packf2(mm, ss),
                           __ATOMIC_RELAXED, __HIP_MEMORY_SCOPE_AGENT);
      __builtin_amdgcn_s_waitcnt(0);
      if (lane == 0)
        __hip_atomic_store(&tplE[((size_t)par * NT + t) * 16], epoch,
                           __ATOMIC_RELAXED, __HIP_MEMORY_SCOPE_AGENT);
    }
    __syncthreads();  // drains all waves' pc stores
    if (tid == 0)
      __hip_atomic_store(&pcE[((size_t)par * NCmax + c) * 16], epoch,
                         __ATOMIC_RELAXED, __HIP_MEMORY_SCOPE_AGENT);
    // ---- P4: wave 0 polls sibling chunk epochs; then all combine -> V ----
    if (wv == 0) {
      bool need = lane < cN;
      unsigned* ce = pcE + (size_t)par * NCmax * 16;
      for (;;) {
        bool ok = !need ||
            (__hip_atomic_load(&ce[(cS + lane) * 16], __ATOMIC_RELAXED, __HIP_MEMORY_SCOPE_AGENT) == epoch);
        if (__all(ok)) break;
        __builtin_amdgcn_s_sleep(1);
      }
    }
    __syncthreads();
    for (int j = tid; j < k; j += 512) {
      u64 pk[12];
#pragma unroll
      for (int q = 0; q < 12; q++)
        pk[q] = (q < cN)
            ? __hip_atomic_load(&pcDp[(size_t)(cS + q) * k + j],
                                __ATOMIC_RELAXED, __HIP_MEMORY_SCOPE_AGENT)
            : packf2(-3.0e38f, 0.f);
      float mm = -3.0e38f;
#pragma unroll
      for (int q = 0; q < 12; q++) mm = fmaxf(mm, plo(pk[q]));
      float ss = 0.f;
#pragma unroll
      for (int q = 0; q < 12; q++) ss += phi(pk[q]) * EX2(plo(pk[q]) - mm);
      V[j] = -(mm + LG2(ss));
    }
    __syncthreads();
  }
  for (int r = tid; r < cR; r += 512) luF[s0 + r] = lu[r];
  if (leader)
    for (int j = tid; j < k; j += 512) VF[(size_t)t * k + j] = V[j];
}

// epilogue (base-2): logits = ln(exp2(M+lu+V)+1e-8); T row scatter into j*17+t
__global__ __launch_bounds__(256) void k_epi(const float* __restrict__ Ms,
    const float* __restrict__ luF, const float* __restrict__ VF,
    const int* __restrict__ perm, const int* __restrict__ tys,
    float* __restrict__ out, int n, int k) {
  __shared__ float vals[KCAP];
  int r = blockIdx.x;
  int i = perm[r], t = tys[r];
  float lu = luF[r];
  const float* Mrow = Ms + (size_t)r * k;
  const float* Vrow = VF + (size_t)t * k;
  for (int j = threadIdx.x; j < k; j += 256) vals[j] = EX2(Mrow[j] + lu + Vrow[j]);
  __syncthreads();
  float* lg = out + (size_t)i * k;
  for (int j = threadIdx.x; j < k; j += 256)
    lg[j] = LG2(vals[j] + 1e-8f) * 0.6931471805599453f;
  int ns = k * NT;
  float* Trow = out + (size_t)n * k + (size_t)i * ns;
  if ((ns & 3) == 0 && (((size_t)n * k) & 3) == 0) {
    int n4 = ns >> 2;
    for (int g4 = threadIdx.x; g4 < n4; g4 += 256) {
      int o0 = g4 << 2;
      float v[4] = {0.f, 0.f, 0.f, 0.f};
#pragma unroll
      for (int s = 0; s < 4; s++) {
        int o = o0 + s;
        int j = o / NT;
        int tt = o - j * NT;
        if (tt == t) v[s] = vals[j];
      }
      *(float4*)(Trow + o0) = make_float4(v[0], v[1], v[2], v[3]);
    }
  } else {
    for (int o = threadIdx.x; o < ns; o += 256) {
      int j = o / NT;
      int tt = o - j * NT;
      Trow[o] = (tt == t) ? vals[j] : 0.f;
    }
  }
}

extern "C" void kernel_launch(void* const* d_in, const int* in_sizes, int n_in,
                              void* d_out, int out_size, void* d_ws, size_t ws_size,
                              hipStream_t stream) {
  const float* emb = (const float*)d_in[0];
  const float* W1  = (const float*)d_in[1];
  const float* b1  = (const float*)d_in[2];
  const float* P   = (const float*)d_in[3];
  const int*   jt  = (const int*)d_in[4];
  (void)n_in; (void)ws_size;

  const int n = in_sizes[4];
  const int H = in_sizes[2];
  const int D = in_sizes[1] / H;
  const int k = out_size / (n * (NT + 1));
  const int nslots = k * NT;
  const float tm_last = (float)((n - nslots) > 1 ? (n - nslots) : 1);
  const float l2tm = log2f(tm_last);
  const int NCmax = NT + (n + CH - 1) / CH;

  char* w = (char*)d_ws;
  size_t off = 0;
  auto take = [&](size_t bytes) -> char* {
    char* p = w + off;
    off = (off + bytes + 255) & ~(size_t)255;
    return p;
  };
  int*      meta = (int*)take(4096);
  int*      perm = (int*)take((size_t)n * 4);
  int*      tys  = (int*)take((size_t)n * 4);
  float*    h    = (float*)take((size_t)n * H * 4);
  float*    hsq  = (float*)take((size_t)n * 4);
  float*    psq  = (float*)take((size_t)k * 4);
  float*    Ms   = (float*)take((size_t)n * k * 4);
  u64*      pcD  = (u64*)take((size_t)2 * NCmax * k * 8);
  unsigned* pcE  = (unsigned*)take((size_t)2 * NCmax * 64);
  u64*      plD  = (u64*)take((size_t)2 * NCmax * 64);
  unsigned* plE  = (unsigned*)take((size_t)2 * NCmax * 64);
  u64*      tplD = (u64*)take((size_t)2 * NT * 64);
  unsigned* tplE = (unsigned*)take((size_t)2 * NT * 64);
  float*    luF  = (float*)take((size_t)n * 4);
  float*    VF   = (float*)take((size_t)NT * k * 4);

  (void)hipMemsetAsync(meta, 0, 4096, stream);
  (void)hipMemsetAsync(pcE, 0, (size_t)2 * NCmax * 64, stream);
  (void)hipMemsetAsync(plE, 0, (size_t)2 * NCmax * 64, stream);
  (void)hipMemsetAsync(tplE, 0, (size_t)2 * NT * 64, stream);
  k_hist<<<(n + 255) / 256, 256, 0, stream>>>(jt, n, meta);
  k_scatter<<<(n + 255) / 256, 256, 0, stream>>>(jt, n, meta, perm, tys);
  k_hgemm<<<dim3(n / 64, H / 64), dim3(256), 0, stream>>>(emb, W1, b1, h, n, D, H);
  k_norms<<<(n + k + 3) / 4, 256, 0, stream>>>(h, P, hsq, psq, n, H, k);
  k_msort<<<dim3(n / 64, (k + 63) / 64), dim3(256), 0, stream>>>(h, P, hsq, psq, perm, Ms, n, H, k);
  k_sink<<<NCmax, 512, 0, stream>>>(Ms, meta, pcD, pcE, plD, plE, tplD, tplE,
                                    luF, VF, k, NCmax, l2tm);
  k_epi<<<n, 256, 0, stream>>>(Ms, luF, VF, perm, tys, (float*)d_out, n, k);
}